// Round 4
// baseline (1407.831 us; speedup 1.0000x reference)
//
#include <hip/hip_runtime.h>
#include <hip/hip_bf16.h>

typedef unsigned short u16;
typedef unsigned int   u32;
typedef __bf16 bf16x8 __attribute__((ext_vector_type(8)));
typedef float  f32x4  __attribute__((ext_vector_type(4)));

#define AS1 __attribute__((address_space(1)))
#define AS3 __attribute__((address_space(3)))

__device__ __forceinline__ u16 f2bf(float f){
    u32 u = __float_as_uint(f);
    u32 r = u + 0x7fffu + ((u>>16)&1u);
    return (u16)(r>>16);
}
__device__ __forceinline__ float bf2f(u16 u){ return __uint_as_float(((u32)u)<<16); }

// ---------------- degree (int) ----------------
__global__ void k_deg(const int* __restrict__ dst, int* __restrict__ degi, int E){
    int e = blockIdx.x*256 + threadIdx.x;
    if (e < E) atomicAdd(&degi[dst[e]], 1);
}

// single-block exclusive scan of degi -> row_ptr, cursor; row_ptr[n]=E
__global__ __launch_bounds__(1024) void k_scan(const int* __restrict__ degi,
        int* __restrict__ row_ptr, int* __restrict__ cursor, int n, int E)
{
    __shared__ int tot[1024];
    const int t = threadIdx.x;
    const int per = (n + 1023) >> 10;
    const int base = t*per;
    int s = 0;
    for (int i = 0; i < per; i++){
        int idx = base + i;
        if (idx < n) s += degi[idx];
    }
    tot[t] = s;
    __syncthreads();
    for (int off = 1; off < 1024; off <<= 1){
        int u = (t >= off) ? tot[t-off] : 0;
        __syncthreads();
        tot[t] += u;
        __syncthreads();
    }
    int run = tot[t] - s;     // exclusive start of this thread's chunk
    for (int i = 0; i < per; i++){
        int idx = base + i;
        if (idx < n){
            int d = degi[idx];
            row_ptr[idx] = run;
            cursor[idx]  = run;
            run += d;
        }
    }
    if (t == 0) row_ptr[n] = E;
}

// degi -> invdeg; rw0 = degc^2 (so rw0*invdeg = degc = RWSE col 0); sc0 = degc
__global__ void k_degc(const int* __restrict__ degi, float* __restrict__ invdeg,
                       float* __restrict__ rw0, float* __restrict__ sc0, int n){
    int v = blockIdx.x*256 + threadIdx.x;
    if (v < n){
        int d = degi[v];
        float c = d == 0 ? 1.f : (float)d;
        invdeg[v] = 1.f/c;
        rw0[v] = c*c;
        sc0[v] = c;
    }
}

// CSR fill: slot = cursor[dst]++; esrc[slot] = src; perm[e] = slot
__global__ void k_fill(const int* __restrict__ src, const int* __restrict__ dst,
                       int* __restrict__ cursor, int* __restrict__ esrc,
                       int* __restrict__ perm, int E){
    int e = blockIdx.x*256 + threadIdx.x;
    if (e < E){
        int pos = atomicAdd(&cursor[dst[e]], 1);
        esrc[pos] = src[e];
        perm[e] = pos;
    }
}

// gather RWSE step: rw_out[v] = sum_j sc_in[esrc[j]]; sc_out = rw_out*invdeg
__global__ void k_rwse_g(const float* __restrict__ sc_in, float* __restrict__ rw_out,
                         float* __restrict__ sc_out, const float* __restrict__ invdeg,
                         const int* __restrict__ row_ptr, const int* __restrict__ esrc,
                         int n){
    int v = blockIdx.x*256 + threadIdx.x;
    if (v >= n) return;
    int j0 = row_ptr[v], j1 = row_ptr[v+1];
    float a = 0.f;
    for (int j = j0; j < j1; j++) a += sc_in[esrc[j]];
    rw_out[v] = a;
    sc_out[v] = a*invdeg[v];
}

// out0 = relu([n_feat, rwse] @ lin0_w + lin0_b)   (fp32)
__global__ void k_finalize(const float* __restrict__ nfeat, const float* __restrict__ rw,
                           const float* __restrict__ invdeg,
                           const float* __restrict__ lw, const float* __restrict__ lb,
                           float* __restrict__ out0, int n){
    __shared__ float lwl[1024];
    __shared__ float lbl[32];
    __shared__ float nfl[8][32];
    int tid = threadIdx.x;
    for (int i = tid; i < 1024; i += 256) lwl[i] = lw[i];
    if (tid < 32) lbl[tid] = lb[tid];
    int slot = tid>>5, o = tid&31;
    int v = blockIdx.x*8 + slot;
    float nfv = 0.f;
    if (v < n){
        nfv = (o < 16) ? nfeat[(size_t)v*16 + o]
                       : rw[(size_t)(o-16)*n + v]*invdeg[v];
    }
    nfl[slot][o] = nfv;
    __syncthreads();
    if (v < n){
        float a = lbl[o];
        #pragma unroll
        for (int j = 0; j < 32; j++) a += nfl[slot][j]*lwl[j*32+o];
        out0[(size_t)v*32 + o] = a > 0.f ? a : 0.f;
    }
}

// WT[n*1024+k] = bf16(w[k*1024+n])  (fp32 -> bf16, 1024x1024)
__global__ void k_transpose(const float* __restrict__ w, u16* __restrict__ wt){
    __shared__ float t[32][33];
    int bx = blockIdx.x & 31, by = blockIdx.x >> 5;
    int x = threadIdx.x & 31, y = threadIdx.x >> 5;
    #pragma unroll
    for (int i = 0; i < 32; i += 8)
        t[y+i][x] = w[(size_t)(by*32 + y + i)*1024 + bx*32 + x];
    __syncthreads();
    #pragma unroll
    for (int i = 0; i < 32; i += 8)
        wt[(size_t)(bx*32 + y + i)*1024 + by*32 + x] = f2bf(t[x][y+i]);
}

// Pre-pass: A fp32 -> bf16 (rounded), plus gate[e] = sigmoid(A[e,:] . gw + gb) in fp32.
__global__ __launch_bounds__(256) void k_prep(
    const float* __restrict__ A, const float* __restrict__ gw,
    const float* __restrict__ gb, u16* __restrict__ Abf,
    float* __restrict__ gate, int E)
{
    __shared__ f32x4 gwl[256];
    const int tid = threadIdx.x;
    const int wave = tid>>6, lane = tid&63;
    gwl[tid] = ((const f32x4*)gw)[tid];
    __syncthreads();
    const int row = blockIdx.x*4 + wave;
    if (row >= E) return;
    const f32x4* ar = (const f32x4*)(A + (size_t)row*1024);
    ushort4* br = (ushort4*)(Abf + (size_t)row*1024);
    float g = 0.f;
    #pragma unroll
    for (int j = 0; j < 4; j++){
        const int idx = j*64 + lane;
        f32x4 v = ar[idx];
        f32x4 w4 = gwl[idx];
        g += v.x*w4.x + v.y*w4.y + v.z*w4.z + v.w*w4.w;
        ushort4 o;
        o.x = f2bf(v.x); o.y = f2bf(v.y); o.z = f2bf(v.z); o.w = f2bf(v.w);
        br[idx] = o;
    }
    #pragma unroll
    for (int m = 32; m >= 1; m >>= 1) g += __shfl_xor(g, m);
    if (lane == 0) gate[row] = 1.f/(1.f + __expf(-(g + gb[0])));
}

// W = relu(A @ B + bias) * gate; rows stored PERMUTED into CSR slot order
// (perm[row]) so the message pass reads W as a pure sequential stream.
// Row-contiguous staging + chunk XOR swizzle; 3-deep circular buffer,
// counted vmcnt(4), one raw barrier per K-step.
__global__ __launch_bounds__(256) void k_gemm(
    const u16* __restrict__ A, const u16* __restrict__ BT,
    const float* __restrict__ bias, const float* __restrict__ gate,
    const int* __restrict__ perm, u16* __restrict__ Wout, int E)
{
    __shared__ __align__(16) u16 lds_a[3*128*32];  // 3 bufs x [m=128][c=4][8]
    __shared__ __align__(16) u16 lds_b[3*128*32];  // 3 bufs x [n=128][c=4][8]
    __shared__ float gate_lds[128];
    __shared__ float bias_lds[128];
    __shared__ int   perm_lds[128];

    const int tid  = threadIdx.x;
    const int wave = tid>>6, lane = tid&63;
    const int wm = wave>>1, wn = wave&1;
    const int ql = lane>>4, rl = lane&15;

    const int id  = blockIdx.x;
    const int xcd = id & 7;
    const int s   = id >> 3;
    const int nb  = s & 7;
    const int mb  = (s >> 3)*8 + xcd;
    const int MBtot = (E + 127) >> 7;
    if (mb >= MBtot) return;
    const int m0 = mb<<7, n0 = nb<<7;

    if (tid < 128){
        const int row = m0 + tid;
        const int cr  = row < E ? row : E-1;
        gate_lds[tid] = gate[cr];
        perm_lds[tid] = perm[cr];
    } else {
        bias_lds[tid-128] = bias[n0 + tid - 128];
    }
    __syncthreads();

    const int ci0 = (0*4 + wave)*64 + lane;
    const int ci1 = (1*4 + wave)*64 + lane;
    const int mA0 = ci0>>2, cA0 = ci0&3, qA0 = cA0 ^ ((mA0>>1)&3);
    const int mA1 = ci1>>2, cA1 = ci1&3, qA1 = cA1 ^ ((mA1>>1)&3);
    int rA0 = m0 + mA0; if (rA0 >= E) rA0 = E-1;
    int rA1 = m0 + mA1; if (rA1 >= E) rA1 = E-1;
    const u16* pA0 = A + (size_t)rA0*1024 + qA0*8;
    const u16* pA1 = A + (size_t)rA1*1024 + qA1*8;
    const u16* pB0 = BT + (size_t)(n0 + mA0)*1024 + qA0*8;
    const u16* pB1 = BT + (size_t)(n0 + mA1)*1024 + qA1*8;
    const int cb0 = (0*4 + wave)*64;
    const int cb1 = (1*4 + wave)*64;

#define STAGE(buf)                                                          \
    {                                                                       \
        __builtin_amdgcn_global_load_lds((const AS1 void*)pA0,              \
            (AS3 void*)&lds_a[(buf)*4096 + cb0*8], 16, 0, 0);               \
        __builtin_amdgcn_global_load_lds((const AS1 void*)pB0,              \
            (AS3 void*)&lds_b[(buf)*4096 + cb0*8], 16, 0, 0);               \
        __builtin_amdgcn_global_load_lds((const AS1 void*)pA1,              \
            (AS3 void*)&lds_a[(buf)*4096 + cb1*8], 16, 0, 0);               \
        __builtin_amdgcn_global_load_lds((const AS1 void*)pB1,              \
            (AS3 void*)&lds_b[(buf)*4096 + cb1*8], 16, 0, 0);               \
        pA0 += 32; pA1 += 32; pB0 += 32; pB1 += 32;                         \
    }

    const int xr = (rl>>1)&3;
    const int a_off = (wm*64 + rl)*32 + (ql ^ xr)*8;
    const int b_off = (wn*64 + rl)*32 + (ql ^ xr)*8;

    f32x4 acc[4][4];
    #pragma unroll
    for (int i=0;i<4;i++)
    #pragma unroll
        for (int j=0;j<4;j++) acc[i][j] = (f32x4){0.f,0.f,0.f,0.f};

    STAGE(0)
    STAGE(1)
    asm volatile("s_waitcnt vmcnt(4)" ::: "memory");
    __builtin_amdgcn_s_barrier();

    int bc = 0;
    for (int t = 0; t < 32; ++t){
        if (t + 2 < 32){
            int bs = bc + 2; if (bs >= 3) bs -= 3;
            STAGE(bs)
        }

        const u16* la = &lds_a[bc*4096];
        const u16* lb = &lds_b[bc*4096];
        bf16x8 af[4], bfr[4];
        #pragma unroll
        for (int tt=0;tt<4;tt++){
            af[tt]  = *(const bf16x8*)&la[a_off + tt*512];
            bfr[tt] = *(const bf16x8*)&lb[b_off + tt*512];
        }
        #pragma unroll
        for (int mt=0;mt<4;mt++)
        #pragma unroll
            for (int nt=0;nt<4;nt++)
                acc[mt][nt] = __builtin_amdgcn_mfma_f32_16x16x32_bf16(af[mt], bfr[nt], acc[mt][nt], 0,0,0);

        if (t + 2 < 32)      asm volatile("s_waitcnt vmcnt(4)" ::: "memory");
        else if (t + 1 < 32) asm volatile("s_waitcnt vmcnt(0)" ::: "memory");
        if (t + 1 < 32) __builtin_amdgcn_s_barrier();

        bc = bc + 1; if (bc >= 3) bc -= 3;
    }
#undef STAGE

    float bcol[4];
    #pragma unroll
    for (int nt=0;nt<4;nt++) bcol[nt] = bias_lds[wn*64 + nt*16 + rl];

    #pragma unroll
    for (int mt=0;mt<4;mt++){
        const int rloc0 = wm*64 + mt*16 + ql*4;
        #pragma unroll
        for (int r=0;r<4;r++){
            const int rloc = rloc0 + r;
            const int row = m0 + rloc;
            if (row < E){
                const float g = gate_lds[rloc];
                u16* wrow = Wout + (size_t)perm_lds[rloc]*1024 + n0 + wn*64 + rl;
                #pragma unroll
                for (int nt=0;nt<4;nt++){
                    float v = acc[mt][nt][r] + bcol[nt];
                    v = v > 0.f ? v : 0.f;
                    wrow[nt*16] = f2bf(v*g);
                }
            }
        }
    }
}

// Fused message+aggregate+node-update, CSR gather form (no atomics, no neigh).
// One 32-lane slot per node; lane l owns h=l. Per edge: lane loads its own
// x_l = out[s*32+l] and 64B contiguous of W (row in CSR slot order); 32-vec
// per-lane accumulator; 5-step shfl transpose-reduce -> msg[l] at lane l;
// then m=relu(msg*invdeg+out+cb) and [m,out]@mw+mb via 64 shfl.
__global__ __launch_bounds__(256) void k_msgnode(
    const float* __restrict__ outc, const u16* __restrict__ W,
    const int* __restrict__ row_ptr, const int* __restrict__ esrc,
    const float* __restrict__ invdeg, const float* __restrict__ cbv,
    const float* __restrict__ mw, const float* __restrict__ mb,
    float* __restrict__ outn, int n)
{
    __shared__ float mwl[2048];
    const int tid = threadIdx.x;
    for (int i = tid; i < 2048; i += 256) mwl[i] = mw[i];
    __syncthreads();
    const int slot = tid>>5, l = tid&31;
    const int v = blockIdx.x*8 + slot;
    if (v >= n) return;

    const int j0 = row_ptr[v], j1 = row_ptr[v+1];
    float acc[32];
    #pragma unroll
    for (int i=0;i<32;i++) acc[i] = 0.f;

    for (int j = j0; j < j1; j++){
        const int s = esrc[j];
        const float xl = outc[(size_t)s*32 + l];
        const uint4* wq = (const uint4*)(W + (size_t)j*1024 + l*32);
        #pragma unroll
        for (int c = 0; c < 4; c++){
            uint4 q = wq[c];
            u32 ws[4] = {q.x, q.y, q.z, q.w};
            #pragma unroll
            for (int k = 0; k < 4; k++){
                float flo = __uint_as_float(ws[k] << 16);
                float fhi = __uint_as_float(ws[k] & 0xffff0000u);
                acc[c*8 + k*2]     += xl*flo;
                acc[c*8 + k*2 + 1] += xl*fhi;
            }
        }
    }

    // transpose-reduce: lane l ends with msg[l]
    float r1[16], r2[8], r3[4], r4[2], msg;
    {
        const int b0 = l & 1;
        #pragma unroll
        for (int i=0;i<16;i++){
            float keep = b0 ? acc[2*i+1] : acc[2*i];
            float send = b0 ? acc[2*i]   : acc[2*i+1];
            r1[i] = keep + __shfl_xor(send, 1, 32);
        }
        const int b1 = (l>>1)&1;
        #pragma unroll
        for (int i=0;i<8;i++){
            float keep = b1 ? r1[2*i+1] : r1[2*i];
            float send = b1 ? r1[2*i]   : r1[2*i+1];
            r2[i] = keep + __shfl_xor(send, 2, 32);
        }
        const int b2 = (l>>2)&1;
        #pragma unroll
        for (int i=0;i<4;i++){
            float keep = b2 ? r2[2*i+1] : r2[2*i];
            float send = b2 ? r2[2*i]   : r2[2*i+1];
            r3[i] = keep + __shfl_xor(send, 4, 32);
        }
        const int b3 = (l>>3)&1;
        #pragma unroll
        for (int i=0;i<2;i++){
            float keep = b3 ? r3[2*i+1] : r3[2*i];
            float send = b3 ? r3[2*i]   : r3[2*i+1];
            r4[i] = keep + __shfl_xor(send, 8, 32);
        }
        const int b4 = (l>>4)&1;
        {
            float keep = b4 ? r4[1] : r4[0];
            float send = b4 ? r4[0] : r4[1];
            msg = keep + __shfl_xor(send, 16, 32);
        }
    }

    const float iv = invdeg[v];
    const float ov = outc[(size_t)v*32 + l];
    float m = msg*iv + ov + cbv[l];
    m = m > 0.f ? m : 0.f;

    float a = mb[l];
    #pragma unroll
    for (int j = 0; j < 32; j++) a += __shfl(m, j, 32)*mwl[j*32 + l];
    #pragma unroll
    for (int j = 0; j < 32; j++) a += __shfl(ov, j, 32)*mwl[(32+j)*32 + l];
    outn[(size_t)v*32 + l] = a;
}

// Fused group-pool + subgraph projection + residual, CSR gather form.
__global__ __launch_bounds__(256) void k_fingroup(
    const float* __restrict__ outc, const int* __restrict__ row_ptr,
    const int* __restrict__ esrc, const float* __restrict__ invdeg,
    const float* __restrict__ sw, const float* __restrict__ sb,
    const float* __restrict__ nfeat, const float* __restrict__ rw,
    float* __restrict__ dout, int n)
{
    __shared__ float swl[2048];
    const int tid = threadIdx.x;
    for (int i = tid; i < 2048; i += 256) swl[i] = sw[i];
    __syncthreads();
    const int slot = tid>>5, l = tid&31;
    const int v = blockIdx.x*8 + slot;
    if (v >= n) return;

    const int j0 = row_ptr[v], j1 = row_ptr[v+1];
    float g = 0.f;
    for (int j = j0; j < j1; j++)
        g += outc[(size_t)esrc[j]*32 + l];
    const float iv = invdeg[v];
    g *= iv;
    const float ov = outc[(size_t)v*32 + l];

    float a = sb[l];
    #pragma unroll
    for (int j = 0; j < 32; j++) a += __shfl(ov, j, 32)*swl[j*32 + l];
    #pragma unroll
    for (int j = 0; j < 32; j++) a += __shfl(g,  j, 32)*swl[(32+j)*32 + l];

    float initv = (l < 16) ? nfeat[(size_t)v*16 + l]
                           : rw[(size_t)(l-16)*n + v]*iv;
    dout[(size_t)v*32 + l] = a + initv;
}

extern "C" void kernel_launch(void* const* d_in, const int* in_sizes, int n_in,
                              void* d_out, int out_size, void* d_ws, size_t ws_size,
                              hipStream_t stream)
{
    const float* n_feat = (const float*)d_in[0];
    const float* e_feat = (const float*)d_in[1];
    const int*   src    = (const int*)d_in[2];
    const int*   dst    = (const int*)d_in[3];
    const float* epw    = (const float*)d_in[4];
    const float* epb    = (const float*)d_in[5];
    const float* gw     = (const float*)d_in[6];
    const float* gb     = (const float*)d_in[7];
    const float* l0w    = (const float*)d_in[8];
    const float* l0b    = (const float*)d_in[9];
    const float* cb     = (const float*)d_in[10];
    const float* mw     = (const float*)d_in[11];
    const float* mbp    = (const float*)d_in[12];
    const float* sw     = (const float*)d_in[13];
    const float* sb     = (const float*)d_in[14];

    const int N = in_sizes[0] / 16;
    const int E = in_sizes[2];

    char* w = (char*)d_ws;
    int*   degi   = (int*)w;    w += (size_t)N*4;
    int*   row_ptr= (int*)w;    w += (size_t)(N+1)*4;
    int*   cursor = (int*)w;    w += (size_t)N*4;
    int*   esrc   = (int*)w;    w += (size_t)E*4;
    int*   perm   = (int*)w;    w += (size_t)E*4;
    float* invdeg = (float*)w;  w += (size_t)N*4;
    float* sc_a   = (float*)w;  w += (size_t)N*4;
    float* sc_b   = (float*)w;  w += (size_t)N*4;
    float* rw     = (float*)w;  w += (size_t)16*N*4;
    float* out_a  = (float*)w;  w += (size_t)32*N*4;
    float* out_b  = (float*)w;  w += (size_t)32*N*4;
    float* gatev  = (float*)w;  w += (size_t)E*4;
    u16*   wtb    = (u16*)w;    w += (size_t)1024*1024*2;
    u16*   abf    = (u16*)w;    w += (size_t)E*1024*2;
    u16*   wout   = (u16*)w;

    hipMemsetAsync(degi, 0, (size_t)N*4, stream);

    const int EB  = (E + 255)/256, NB = (N + 255)/256;
    const int NB8 = (N + 7)/8;

    // ---- CSR build ----
    k_deg<<<EB,256,0,stream>>>(dst, degi, E);
    k_scan<<<1,1024,0,stream>>>(degi, row_ptr, cursor, N, E);
    k_degc<<<NB,256,0,stream>>>(degi, invdeg, rw, sc_a, N);
    k_fill<<<EB,256,0,stream>>>(src, dst, cursor, esrc, perm, E);

    // ---- RWSE (gather form, no atomics/memsets) ----
    float* scur = sc_a; float* snxt = sc_b;
    for (int t = 0; t < 15; t++){
        k_rwse_g<<<NB,256,0,stream>>>(scur, rw + (size_t)(t+1)*N, snxt,
                                      invdeg, row_ptr, esrc, N);
        float* tmp = scur; scur = snxt; snxt = tmp;
    }
    k_finalize<<<NB8,256,0,stream>>>(n_feat, rw, invdeg, l0w, l0b, out_a, N);

    // ---- edge weights ----
    k_transpose<<<1024,256,0,stream>>>(epw, wtb);
    k_prep<<<(E+3)/4,256,0,stream>>>(e_feat, gw, gb, abf, gatev, E);

    const int MBtot = (E + 127)/128;
    const int grid  = ((MBtot + 7)/8)*64;
    k_gemm<<<grid,256,0,stream>>>(abf, wtb, epb, gatev, perm, wout, E);

    // ---- 3 message-passing iterations (fused, gather form) ----
    float* cur = out_a; float* nxt = out_b;
    for (int it = 0; it < 3; it++){
        k_msgnode<<<NB8,256,0,stream>>>(cur, wout, row_ptr, esrc, invdeg,
                                        cb, mw, mbp, nxt, N);
        float* tmp = cur; cur = nxt; nxt = tmp;
    }

    // ---- group pool + final projection + residual ----
    k_fingroup<<<NB8,256,0,stream>>>(cur, row_ptr, esrc, invdeg, sw, sb,
                                     n_feat, rw, (float*)d_out, N);

    (void)n_in; (void)out_size; (void)ws_size;
}